// Round 5
// baseline (106.678 us; speedup 1.0000x reference)
//
#include <hip/hip_runtime.h>
#include <math.h>

// RingConv2d = atan2( sum sin(x-w), sum cos(x-w) ) over 3x3xC patches.
//   cos(x-w) = cx*cw + sx*sw ; sin(x-w) = sx*cw - cx*sw   (ringify is a no-op)
// => 4 standard 3x3 convs on (cos x, sin x) planes + atan2 epilogue.
// Weight table entry: {cw, -sw, sw, 0} so inner loop is 4 fmaf with no negation.
//   ax += cx*e.x + sx*e.z ;  ay += sx*e.x + cx*e.y
// Workspace-safe: fast path (f16 sincos planes + f32x4 weight table, 2.3 MB)
// only when ws_size allows; otherwise a ZERO-workspace fallback computes all
// trig in-kernel. Branch is on ws_size (constant) -> same work every call.

typedef float     f32x2 __attribute__((ext_vector_type(2)));
typedef float     f32x4 __attribute__((ext_vector_type(4)));
typedef _Float16  h16x2 __attribute__((ext_vector_type(2)));
typedef unsigned int u32;
typedef u32       u32x4 __attribute__((ext_vector_type(4)));

#define B_   4
#define C_   32
#define H_   64
#define W_   64
#define O_   64
#define OC   2            // output channels per block
#define NOG  (O_ / OC)    // 32 o-groups
#define CG   4            // input channels per LDS stage
#define HW   (H_ * W_)
#define NPIX (B_ * C_ * HW)                 // 524288
#define WT_ENTRIES (C_ * NOG * 9 * OC)      // 18432 f32x4
#define WT_BYTES   (WT_ENTRIES * 16)        // 294912
#define PLANES_BYTES (NPIX * 4)             // 2 MB (u32 = packed f16 cos,sin)
#define NEED_WS ((size_t)WT_BYTES + (size_t)PLANES_BYTES)

// ---- prep (fast path only): weight trig table + packed-f16 sincos planes
__global__ __launch_bounds__(256) void ring_prep(const float* __restrict__ x,
                                                 const float* __restrict__ w,
                                                 f32x4* __restrict__ wt,
                                                 u32* __restrict__ planes) {
    const int bid = blockIdx.x;
    const int tid = threadIdx.x;
    if (bid < 72) {
        // 72*256 == 18432 == O*C*9.  src idx = (o*C + c)*9 + ij
        int idx = bid * 256 + tid;
        int o  = idx / (C_ * 9);
        int r  = idx % (C_ * 9);
        int c  = r / 9;
        int ij = r % 9;
        float s, cc;
        __sincosf(w[idx], &s, &cc);
        wt[((c * NOG + o / OC) * 9 + ij) * OC + (o % OC)] = (f32x4){cc, -s, s, 0.f};
    } else {
        // 512 blocks * 256 threads * 4 px = NPIX
        int i = (bid - 72) * 256 + tid;
        f32x4 xv = ((const f32x4*)x)[i];
        u32x4 pk;
#pragma unroll
        for (int j = 0; j < 4; ++j) {
            float s, cc;
            __sincosf(xv[j], &s, &cc);
            h16x2 h = {(_Float16)cc, (_Float16)s};
            pk[j] = __builtin_bit_cast(u32, h);
        }
        ((u32x4*)planes)[i] = pk;
    }
}

// ---- main conv.  PLANES=true: read precomputed tables from d_ws.
//      PLANES=false: zero-workspace, all trig computed inline.
template <bool PLANES>
__global__ __launch_bounds__(256, 8) void ring_conv(const float* __restrict__ xraw,
                                                    const u32* __restrict__ planes,
                                                    const float* __restrict__ wraw,
                                                    const f32x4* __restrict__ wt,
                                                    float* __restrict__ out) {
    __shared__ f32x2 sm[CG][18][18];        // 10368 B

    const int tid = threadIdx.x;
    const int tile = blockIdx.x;            // 16 tiles of 16x16
    const int tile_y = (tile >> 2) * 16;
    const int tile_x = (tile & 3) * 16;
    const int og = blockIdx.y;              // 32 o-groups
    const int ob = og * OC;
    const int b  = blockIdx.z;

    const int ty = tid >> 4;
    const int tx = tid & 15;

    float ax[OC], ay[OC];
#pragma unroll
    for (int o = 0; o < OC; ++o) { ax[o] = 0.f; ay[o] = 0.f; }

    const int pbase = b * C_ * HW;

    for (int cg = 0; cg < C_; cg += CG) {
        __syncthreads();
        // stage CG x 18 x 18 (cos,sin) pairs; zero halo -> (1,0)
#pragma unroll 1
        for (int i = tid; i < CG * 18 * 18; i += 256) {
            int c  = i / 324;
            int rr = i % 324;
            int r  = rr / 18;
            int cl = rr % 18;
            int hh = tile_y + r - 1;
            int ww = tile_x + cl - 1;
            f32x2 v = (f32x2){1.f, 0.f};
            if ((unsigned)hh < (unsigned)H_ && (unsigned)ww < (unsigned)W_) {
                int gidx = pbase + (cg + c) * HW + hh * W_ + ww;
                if (PLANES) {
                    h16x2 h = __builtin_bit_cast(h16x2, planes[gidx]);
                    v = (f32x2){(float)h.x, (float)h.y};
                } else {
                    float s, cc;
                    __sincosf(xraw[gidx], &s, &cc);
                    v = (f32x2){cc, s};
                }
            }
            sm[c][r][cl] = v;
        }
        __syncthreads();

#pragma unroll 1
        for (int c = 0; c < CG; ++c) {
            f32x2 P[9];
#pragma unroll
            for (int i = 0; i < 3; ++i)
#pragma unroll
                for (int j = 0; j < 3; ++j)
                    P[i * 3 + j] = sm[c][ty + i][tx + j];

            f32x4 efb[9 * OC];
            const f32x4* wp = nullptr;
            if (PLANES) {
                wp = wt + (size_t)((cg + c) * NOG + og) * (9 * OC);
            } else {
#pragma unroll
                for (int o = 0; o < OC; ++o)
#pragma unroll
                    for (int ij = 0; ij < 9; ++ij) {
                        float wv = wraw[((ob + o) * C_ + cg + c) * 9 + ij];
                        float s, cc;
                        __sincosf(wv, &s, &cc);
                        efb[ij * OC + o] = (f32x4){cc, -s, s, 0.f};
                    }
            }

#pragma unroll
            for (int ij = 0; ij < 9; ++ij) {
#pragma unroll
                for (int o = 0; o < OC; ++o) {
                    f32x4 e = PLANES ? wp[ij * OC + o] : efb[ij * OC + o];
                    float cx = P[ij].x, sx = P[ij].y;
                    ax[o] = fmaf(cx, e.x, fmaf(sx, e.z, ax[o]));
                    ay[o] = fmaf(sx, e.x, fmaf(cx, e.y, ay[o]));
                }
            }
        }
    }

    const int h = tile_y + ty;
    const int wcol = tile_x + tx;
    float* op = out + (size_t)(b * O_ + ob) * HW + h * W_ + wcol;
#pragma unroll
    for (int o = 0; o < OC; ++o)
        op[(size_t)o * HW] = atan2f(ay[o], ax[o]);
}

extern "C" void kernel_launch(void* const* d_in, const int* in_sizes, int n_in,
                              void* d_out, int out_size, void* d_ws, size_t ws_size,
                              hipStream_t stream) {
    const float* x = (const float*)d_in[0];   // (4,32,64,64) f32
    const float* w = (const float*)d_in[1];   // (64,32,3,3)  f32
    float* out = (float*)d_out;               // (4,64,64,64) f32

    dim3 grid((H_ / 16) * (W_ / 16), NOG, B_);

    if (ws_size >= NEED_WS) {
        f32x4* wt   = (f32x4*)d_ws;
        u32* planes = (u32*)((char*)d_ws + WT_BYTES);
        ring_prep<<<dim3(72 + NPIX / 1024), dim3(256), 0, stream>>>(x, w, wt, planes);
        ring_conv<true><<<grid, dim3(256), 0, stream>>>(x, planes, w, wt, out);
    } else {
        // zero-workspace fallback: all trig inline
        ring_conv<false><<<grid, dim3(256), 0, stream>>>(x, nullptr, w, nullptr, out);
    }
}